// Round 1
// baseline (165.674 us; speedup 1.0000x reference)
//
#include <hip/hip_runtime.h>
#include <hip/hip_bf16.h>

// Single-head causal self-attention, B=4 T=4096 C=1024 H=128, f32 in/out.
// Pipeline: prep_w (W -> Wt bf16 transposed) ; proj (x@W -> Qb,Kb bf16 + Vt
// transposed bf16) ; attn (flash causal, 16x16x32 bf16 MFMA).
// ws map (bytes): Wt[0, 786432) Qb[786432, +4MB) Kb[+4MB) Vt[+4MB) = 13369344 total.

typedef unsigned short u16;
typedef __attribute__((ext_vector_type(8))) __bf16 bf16x8;
typedef __attribute__((ext_vector_type(8))) u16 u16x8;
typedef __attribute__((ext_vector_type(4))) u16 u16x4;
typedef __attribute__((ext_vector_type(4))) float f32x4;

#define T_DIM 4096
#define B_DIM 4
#define C_DIM 1024
#define H_DIM 128

static __device__ __forceinline__ f32x4 mfma16x16(u16x8 a, u16x8 b, f32x4 c) {
  return __builtin_amdgcn_mfma_f32_16x16x32_bf16(
      __builtin_bit_cast(bf16x8, a), __builtin_bit_cast(bf16x8, b), c, 0, 0, 0);
}

static __device__ __forceinline__ u16 f2bf(float f) {
  __hip_bfloat16 h = __float2bfloat16(f);
  return __builtin_bit_cast(u16, h);
}

// ---------------------------------------------------------------- prep_w ----
// Wt[w][n][k] = bf16(W_w[k][n]); 3 x [128][1024] bf16.
__global__ __launch_bounds__(256) void prep_w_kernel(
    const float* __restrict__ wk, const float* __restrict__ wq,
    const float* __restrict__ wv, u16* __restrict__ Wt) {
  int idx = blockIdx.x * 256 + threadIdx.x;  // 3*128*1024 = 393216 exact
  int w = idx >> 17;
  int r = idx & 131071;
  int n = r >> 10;
  int k = r & 1023;
  const float* W = (w == 0) ? wk : (w == 1) ? wq : wv;
  Wt[idx] = f2bf(W[k * H_DIM + n]);
}

// ------------------------------------------------------------------ proj ----
// grid (128, 3): blockIdx.x = m-tile (128 rows of B*T), blockIdx.y = which W.
// Per block: 128x128 output tile, K-loop of 64, 4 waves (2x2 of 64x64).
__global__ __launch_bounds__(256) void proj_kernel(
    const float* __restrict__ x, const u16* __restrict__ Wt,
    u16* __restrict__ Qb, u16* __restrict__ Kb, u16* __restrict__ Vt) {
  __shared__ __attribute__((aligned(16))) u16 smem[2 * 128 * 72];
  u16* Al = smem;            // x tile    [128][64] pad-> stride 72
  u16* Bl = smem + 128 * 72; // Wt tile   [128][64] pad-> stride 72
  const int m0 = blockIdx.x * 128;
  const int w = blockIdx.y;
  const u16* Wtw = Wt + w * (H_DIM * C_DIM);
  const int t = threadIdx.x;
  const int wave = t >> 6, lane = t & 63;
  const int wm = wave >> 1, wn = wave & 1;
  const int g = lane >> 4, lq = lane & 15;

  f32x4 acc[4][4] = {};

  const int arow = t >> 4, acol = (t & 15) * 4;  // A: 16 rows/pass x 16B-f32
  const int brow = t >> 3, bcol = (t & 7) * 8;   // B: 32 rows/pass x 16B-bf16

  for (int k0 = 0; k0 < C_DIM; k0 += 64) {
    __syncthreads();
#pragma unroll
    for (int p = 0; p < 8; ++p) {  // stage x: f32 -> bf16
      int r = p * 16 + arow;
      float4 v = *(const float4*)&x[(size_t)(m0 + r) * C_DIM + k0 + acol];
      u16x4 bv;
      bv.x = f2bf(v.x); bv.y = f2bf(v.y); bv.z = f2bf(v.z); bv.w = f2bf(v.w);
      *(u16x4*)&Al[r * 72 + acol] = bv;
    }
#pragma unroll
    for (int p = 0; p < 4; ++p) {  // stage Wt (already bf16, row-major n,k)
      int n = p * 32 + brow;
      *(u16x8*)&Bl[n * 72 + bcol] = *(const u16x8*)&Wtw[n * C_DIM + k0 + bcol];
    }
    __syncthreads();
#pragma unroll
    for (int kk = 0; kk < 2; ++kk) {
      u16x8 af[4], bfr[4];
#pragma unroll
      for (int i = 0; i < 4; ++i)
        af[i] = *(const u16x8*)&Al[(wm * 64 + i * 16 + lq) * 72 + kk * 32 + g * 8];
#pragma unroll
      for (int j = 0; j < 4; ++j)
        bfr[j] = *(const u16x8*)&Bl[(wn * 64 + j * 16 + lq) * 72 + kk * 32 + g * 8];
#pragma unroll
      for (int i = 0; i < 4; ++i)
#pragma unroll
        for (int j = 0; j < 4; ++j)
          acc[i][j] = mfma16x16(af[i], bfr[j], acc[i][j]);
    }
  }

  if (w < 2) {
    // row-major bf16 [16384][128]; D-layout: row = 4*g+r, col = lq per 16x16.
    u16* O = (w == 0) ? Kb : Qb;
#pragma unroll
    for (int i = 0; i < 4; ++i)
#pragma unroll
      for (int j = 0; j < 4; ++j)
#pragma unroll
        for (int r = 0; r < 4; ++r)
          O[(size_t)(m0 + wm * 64 + i * 16 + g * 4 + r) * H_DIM + wn * 64 +
            j * 16 + lq] = f2bf(acc[i][j][r]);
  } else {
    // V: transpose in LDS, store Vt[b][h][t] coalesced.
    __syncthreads();
    u16* Tl = smem;  // [128 h][136 m] bf16 (34816B <= 36864B)
#pragma unroll
    for (int i = 0; i < 4; ++i)
#pragma unroll
      for (int j = 0; j < 4; ++j)
#pragma unroll
        for (int r = 0; r < 4; ++r)
          Tl[(wn * 64 + j * 16 + lq) * 136 + wm * 64 + i * 16 + g * 4 + r] =
              f2bf(acc[i][j][r]);
    __syncthreads();
    const int b = m0 >> 12;
    const int t0 = m0 & 4095;
    const int h = t >> 1;
    const int mcb = (t & 1) * 64;
#pragma unroll
    for (int p = 0; p < 8; ++p) {
      *(u16x8*)&Vt[(size_t)b * (H_DIM * T_DIM) + (size_t)h * T_DIM + t0 + mcb +
                   p * 8] = *(const u16x8*)&Tl[h * 136 + mcb + p * 8];
    }
  }
}

// ------------------------------------------------------------------ attn ----
// grid 256: b = bid&3, qt = 63-(bid>>2) (heavy q-tiles first). 4 waves x 16
// q-rows = QBLK 64, KVBLK 64. Online softmax f32; P via per-wave LDS to get
// A-layout for PV; V consumed from transposed Vt so B-frags are contiguous.
__global__ __launch_bounds__(256) void attn_kernel(
    const u16* __restrict__ Qb, const u16* __restrict__ Kb,
    const u16* __restrict__ Vt, float* __restrict__ out) {
  __shared__ __attribute__((aligned(16))) u16 Kl[64 * 136];
  __shared__ __attribute__((aligned(16))) u16 Vl[128 * 72];
  __shared__ __attribute__((aligned(16))) u16 Pl[4][16 * 72];
  const int t = threadIdx.x;
  const int wave = t >> 6, lane = t & 63;
  const int g = lane >> 4, lq = lane & 15;
  const int bid = blockIdx.x;
  const int b = bid & 3;
  const int qt = 63 - (bid >> 2);
  const int q0 = qt * 64;

  u16x8 qf[4];  // Q hoisted: 16 rows x 128 cols, A-frag layout
  {
    const u16* Qp = Qb + (size_t)(b * T_DIM + q0 + wave * 16 + lq) * H_DIM;
#pragma unroll
    for (int c = 0; c < 4; ++c) qf[c] = *(const u16x8*)&Qp[c * 32 + g * 8];
  }

  f32x4 ao[8] = {};
  float m_run[4], l_run[4];
#pragma unroll
  for (int r = 0; r < 4; ++r) { m_run[r] = -INFINITY; l_run[r] = 0.f; }
  const float scale = 0.08838834764831845f;  // 128^-0.5

  const int krow = t >> 4, kcol = (t & 15) * 8;
  const int vrow = t >> 3, vcol = (t & 7) * 8;
  const u16* Kg0 = Kb + (size_t)b * T_DIM * H_DIM;
  const u16* Vg0 = Vt + (size_t)b * H_DIM * T_DIM;

  for (int kv0 = 0; kv0 <= q0; kv0 += 64) {
    __syncthreads();
#pragma unroll
    for (int p = 0; p < 4; ++p) {  // K tile [64][128] -> [64][136]
      int r = p * 16 + krow;
      *(u16x8*)&Kl[r * 136 + kcol] =
          *(const u16x8*)&Kg0[(size_t)(kv0 + r) * H_DIM + kcol];
    }
#pragma unroll
    for (int p = 0; p < 4; ++p) {  // Vt tile [128][64] -> [128][72]
      int h = p * 32 + vrow;
      *(u16x8*)&Vl[h * 72 + vcol] =
          *(const u16x8*)&Vg0[(size_t)h * T_DIM + kv0 + vcol];
    }
    __syncthreads();

    // S = (Q K^T) * scale : 4 col-frags x 4 k-chunks
    f32x4 s[4];
#pragma unroll
    for (int nf = 0; nf < 4; ++nf) {
      f32x4 a = {0.f, 0.f, 0.f, 0.f};
#pragma unroll
      for (int kk = 0; kk < 4; ++kk) {
        u16x8 kf = *(const u16x8*)&Kl[(nf * 16 + lq) * 136 + kk * 32 + g * 8];
        a = mfma16x16(qf[kk], kf, a);
      }
      s[nf] = a * scale;
    }

    if (kv0 == q0) {  // diagonal tile: causal mask (col > row)
      int row = wave * 16 + g * 4;
#pragma unroll
      for (int nf = 0; nf < 4; ++nf) {
        int col = nf * 16 + lq;
#pragma unroll
        for (int r = 0; r < 4; ++r)
          if (col > row + r) s[nf][r] = -INFINITY;
      }
    }

    // online softmax; rows 4g..4g+3 live in 16-lane group g
    float mloc[4];
#pragma unroll
    for (int r = 0; r < 4; ++r)
      mloc[r] = fmaxf(fmaxf(s[0][r], s[1][r]), fmaxf(s[2][r], s[3][r]));
#pragma unroll
    for (int off = 1; off < 16; off <<= 1)
#pragma unroll
      for (int r = 0; r < 4; ++r)
        mloc[r] = fmaxf(mloc[r], __shfl_xor(mloc[r], off));

    float al[4], ps[4];
#pragma unroll
    for (int r = 0; r < 4; ++r) {
      float mn = fmaxf(m_run[r], mloc[r]);
      al[r] = __expf(m_run[r] - mn);
      m_run[r] = mn;
      ps[r] = 0.f;
    }
#pragma unroll
    for (int nf = 0; nf < 4; ++nf)
#pragma unroll
      for (int r = 0; r < 4; ++r) {
        float p = __expf(s[nf][r] - m_run[r]);
        s[nf][r] = p;
        ps[r] += p;
      }
#pragma unroll
    for (int off = 1; off < 16; off <<= 1)
#pragma unroll
      for (int r = 0; r < 4; ++r) ps[r] += __shfl_xor(ps[r], off);
#pragma unroll
    for (int r = 0; r < 4; ++r) l_run[r] = l_run[r] * al[r] + ps[r];
#pragma unroll
    for (int h8 = 0; h8 < 8; ++h8)
#pragma unroll
      for (int r = 0; r < 4; ++r) ao[h8][r] *= al[r];

    // P (D-layout) -> per-wave LDS -> A-layout frags for PV
#pragma unroll
    for (int nf = 0; nf < 4; ++nf)
#pragma unroll
      for (int r = 0; r < 4; ++r)
        Pl[wave][(g * 4 + r) * 72 + nf * 16 + lq] = f2bf(s[nf][r]);

#pragma unroll
    for (int kk = 0; kk < 2; ++kk) {
      u16x8 pf = *(const u16x8*)&Pl[wave][lq * 72 + kk * 32 + g * 8];
#pragma unroll
      for (int h8 = 0; h8 < 8; ++h8) {
        u16x8 vf = *(const u16x8*)&Vl[(h8 * 16 + lq) * 72 + kk * 32 + g * 8];
        ao[h8] = mfma16x16(pf, vf, ao[h8]);
      }
    }
  }

  float inv[4];
#pragma unroll
  for (int r = 0; r < 4; ++r) inv[r] = 1.f / l_run[r];
  float* Og = out + (size_t)(b * T_DIM + q0 + wave * 16) * H_DIM;
#pragma unroll
  for (int h8 = 0; h8 < 8; ++h8)
#pragma unroll
    for (int r = 0; r < 4; ++r)
      Og[(size_t)(g * 4 + r) * H_DIM + h8 * 16 + lq] = ao[h8][r] * inv[r];
}

// ---------------------------------------------------------------- launch ----
extern "C" void kernel_launch(void* const* d_in, const int* in_sizes, int n_in,
                              void* d_out, int out_size, void* d_ws,
                              size_t ws_size, hipStream_t stream) {
  const float* x = (const float*)d_in[0];
  const float* wk = (const float*)d_in[1];
  const float* wq = (const float*)d_in[2];
  const float* wv = (const float*)d_in[3];
  float* out = (float*)d_out;
  char* ws = (char*)d_ws;

  u16* Wt = (u16*)ws;                           // 786432 B
  u16* Qb = (u16*)(ws + 786432);                // 4 MB
  u16* Kb = (u16*)(ws + 786432 + 4194304);      // 4 MB
  u16* Vt = (u16*)(ws + 786432 + 8388608);      // 4 MB

  prep_w_kernel<<<1536, 256, 0, stream>>>(wk, wq, wv, Wt);
  proj_kernel<<<dim3(128, 3), 256, 0, stream>>>(x, Wt, Qb, Kb, Vt);
  attn_kernel<<<256, 256, 0, stream>>>(Qb, Kb, Vt, out);
}

// Round 2
// 113.859 us; speedup vs baseline: 1.4551x; 1.4551x over previous
//
#include <hip/hip_runtime.h>
#include <hip/hip_bf16.h>

// Single-head causal self-attention, B=4 T=4096 C=1024 H=128, f32 in/out.
// Pipeline: prep_w (W -> Wt bf16 transposed); proj_fused (x@{Wk,Wq,Wv} in one
// pass over x -> Kb, Qb(prescaled), Vt(transposed)); attn (flash causal,
// 16x16x32 bf16 MFMA, KV-SPLIT for occupancy); combine (merge partials).
//
// ws map (bytes):
//   Wt    [0,        786432)
//   Qb    [786432,   +4MB)
//   Kb    [+4MB)
//   Vt    [+4MB)                      -> 13369344
//   Opart [13369344, +1152*32KB)      -> 51118080   (split mode only)
//   ml    [51118080, +589824)         -> 51707904   (split mode only)

typedef unsigned short u16;
typedef __attribute__((ext_vector_type(8))) __bf16 bf16x8;
typedef __attribute__((ext_vector_type(8))) u16 u16x8;
typedef __attribute__((ext_vector_type(4))) u16 u16x4;
typedef __attribute__((ext_vector_type(4))) float f32x4;

#define T_DIM 4096
#define C_DIM 1024
#define H_DIM 128
#define NPB 288          // split entries per batch (CHUNK = 8 kv-tiles = 512)
#define WS_SPLIT_NEED 51707904ull

static __device__ __forceinline__ f32x4 mfma16x16(u16x8 a, u16x8 b, f32x4 c) {
  return __builtin_amdgcn_mfma_f32_16x16x32_bf16(
      __builtin_bit_cast(bf16x8, a), __builtin_bit_cast(bf16x8, b), c, 0, 0, 0);
}

static __device__ __forceinline__ u16 f2bf(float f) {
  __hip_bfloat16 h = __float2bfloat16(f);
  return __builtin_bit_cast(u16, h);
}

// ---------------------------------------------------------------- prep_w ----
__global__ __launch_bounds__(256) void prep_w_kernel(
    const float* __restrict__ wk, const float* __restrict__ wq,
    const float* __restrict__ wv, u16* __restrict__ Wt) {
  int idx = blockIdx.x * 256 + threadIdx.x;  // 3*128*1024 exact
  int w = idx >> 17;
  int r = idx & 131071;
  int n = r >> 10;
  int k = r & 1023;
  const float* W = (w == 0) ? wk : (w == 1) ? wq : wv;
  Wt[idx] = f2bf(W[k * H_DIM + n]);
}

// ------------------------------------------------------------ proj_fused ----
// 256 blocks x 64 rows. One x-tile staging feeds all three Ws.
// wave0 -> Kb, wave1 -> Qb (prescaled by H^-0.5), wave2 -> Vt, wave3 stages.
__global__ __launch_bounds__(256, 1) void proj_kernel(
    const float* __restrict__ x, const u16* __restrict__ Wt,
    u16* __restrict__ Qb, u16* __restrict__ Kb, u16* __restrict__ Vt) {
  __shared__ __attribute__((aligned(16))) u16 smem[64 * 72 + 384 * 72];
  u16* Xl = smem;            // [64][64] pad 72
  u16* Wl = smem + 64 * 72;  // [3*128][64] pad 72
  const int m0 = blockIdx.x * 64;
  const int t = threadIdx.x;
  const int wave = t >> 6, lane = t & 63;
  const int g = lane >> 4, lq = lane & 15;

  f32x4 acc[4][8] = {};

  for (int k0 = 0; k0 < C_DIM; k0 += 64) {
    __syncthreads();
#pragma unroll
    for (int p = 0; p < 4; ++p) {  // stage x: 64x64 f32 -> bf16
      int idx = p * 256 + t;
      int row = idx >> 4, c4 = (idx & 15) * 4;
      float4 v = *(const float4*)&x[(size_t)(m0 + row) * C_DIM + k0 + c4];
      u16x4 bv;
      bv.x = f2bf(v.x); bv.y = f2bf(v.y); bv.z = f2bf(v.z); bv.w = f2bf(v.w);
      *(u16x4*)&Xl[row * 72 + c4] = bv;
    }
#pragma unroll
    for (int p = 0; p < 12; ++p) {  // stage Wt: 384 rows x 64 k
      int idx = p * 256 + t;
      int wrow = idx >> 3, col = (idx & 7) * 8;
      *(u16x8*)&Wl[wrow * 72 + col] =
          *(const u16x8*)&Wt[(size_t)(wrow >> 7) * 131072 +
                             (size_t)(wrow & 127) * 1024 + k0 + col];
    }
    __syncthreads();
    if (wave < 3) {
#pragma unroll
      for (int kk = 0; kk < 2; ++kk) {
        u16x8 af[4], bfr[8];
#pragma unroll
        for (int i = 0; i < 4; ++i)
          af[i] = *(const u16x8*)&Xl[(i * 16 + lq) * 72 + kk * 32 + g * 8];
#pragma unroll
        for (int j = 0; j < 8; ++j)
          bfr[j] = *(const u16x8*)&Wl[(wave * 128 + j * 16 + lq) * 72 +
                                      kk * 32 + g * 8];
#pragma unroll
        for (int i = 0; i < 4; ++i)
#pragma unroll
          for (int j = 0; j < 8; ++j)
            acc[i][j] = mfma16x16(af[i], bfr[j], acc[i][j]);
      }
    }
  }

  const float qscale = 0.08838834764831845f;  // 128^-0.5
  if (wave == 0) {
#pragma unroll
    for (int i = 0; i < 4; ++i)
#pragma unroll
      for (int j = 0; j < 8; ++j)
#pragma unroll
        for (int r = 0; r < 4; ++r)
          Kb[(size_t)(m0 + i * 16 + g * 4 + r) * H_DIM + j * 16 + lq] =
              f2bf(acc[i][j][r]);
  }
  if (wave == 1) {
#pragma unroll
    for (int i = 0; i < 4; ++i)
#pragma unroll
      for (int j = 0; j < 8; ++j)
#pragma unroll
        for (int r = 0; r < 4; ++r)
          Qb[(size_t)(m0 + i * 16 + g * 4 + r) * H_DIM + j * 16 + lq] =
              f2bf(acc[i][j][r] * qscale);
  }
  __syncthreads();
  if (wave == 2) {  // V -> LDS transposed [128 h][64 m] stride 72
#pragma unroll
    for (int i = 0; i < 4; ++i)
#pragma unroll
      for (int j = 0; j < 8; ++j)
#pragma unroll
        for (int r = 0; r < 4; ++r)
          smem[(j * 16 + lq) * 72 + i * 16 + g * 4 + r] = f2bf(acc[i][j][r]);
  }
  __syncthreads();
  {
    const int b = m0 >> 12;
    const int t0 = m0 & 4095;
#pragma unroll
    for (int p = 0; p < 4; ++p) {
      int idx = p * 256 + t;
      int h = idx >> 3, mc = (idx & 7) * 8;
      *(u16x8*)&Vt[(size_t)b * (H_DIM * T_DIM) + (size_t)h * T_DIM + t0 + mc] =
          *(const u16x8*)&smem[h * 72 + mc];
    }
  }
}

// ------------------------------------------------------------------ attn ----
// split: grid (NPB, 4); chunk = 8 kv-tiles (512 pos). Partials to Opart/ml.
// non-split fallback: grid 256 linear, writes out directly.
__global__ __launch_bounds__(256) void attn_kernel(
    const u16* __restrict__ Qb, const u16* __restrict__ Kb,
    const u16* __restrict__ Vt, float* __restrict__ out,
    float* __restrict__ Opart, float* __restrict__ ml, int split) {
  __shared__ __attribute__((aligned(16))) u16 Kl[64 * 136];
  __shared__ __attribute__((aligned(16))) u16 Vl[128 * 72];
  __shared__ __attribute__((aligned(16))) u16 Pl[4][16 * 72];
  const int t = threadIdx.x;
  const int wave = t >> 6, lane = t & 63;
  const int g = lane >> 4, lq = lane & 15;

  int b, qt, kvb, kve, pid;
  if (split) {
    b = blockIdx.y;
    int e = (NPB - 1) - (int)blockIdx.x;  // heavy chunks dispatch first
    int gg = 0;
#pragma unroll
    for (int c = 1; c < 8; ++c)
      if (e >= 4 * c * (c + 1)) gg = c;
    int off = e - 4 * gg * (gg + 1);
    int npc = gg + 1;
    int d = off / npc;
    qt = 8 * gg + d;
    int ch = off - d * npc;
    kvb = ch * 512;
    pid = b * NPB + e;
    int kv_full = qt * 64 + 64;
    kve = (kvb + 512 < kv_full) ? kvb + 512 : kv_full;
  } else {
    b = blockIdx.x & 3;
    qt = 63 - ((int)blockIdx.x >> 2);
    kvb = 0;
    kve = qt * 64 + 64;
    pid = 0;
  }
  const int q0 = qt * 64;

  u16x8 qf[4];  // Q hoisted: 16 rows x 128 cols, A-frag layout (prescaled)
  {
    const u16* Qp = Qb + (size_t)(b * T_DIM + q0 + wave * 16 + lq) * H_DIM;
#pragma unroll
    for (int c = 0; c < 4; ++c) qf[c] = *(const u16x8*)&Qp[c * 32 + g * 8];
  }

  f32x4 ao[8] = {};
  float m_run[4], l_run[4];
#pragma unroll
  for (int r = 0; r < 4; ++r) { m_run[r] = -INFINITY; l_run[r] = 0.f; }

  const int krow = t >> 4, kcol = (t & 15) * 8;
  const int vrow = t >> 3, vcol = (t & 7) * 8;
  const u16* Kg0 = Kb + (size_t)b * T_DIM * H_DIM;
  const u16* Vg0 = Vt + (size_t)b * H_DIM * T_DIM;

  for (int kv0 = kvb; kv0 < kve; kv0 += 64) {
    __syncthreads();
#pragma unroll
    for (int p = 0; p < 4; ++p) {  // K tile [64][128] -> [64][136]
      int r = p * 16 + krow;
      *(u16x8*)&Kl[r * 136 + kcol] =
          *(const u16x8*)&Kg0[(size_t)(kv0 + r) * H_DIM + kcol];
    }
#pragma unroll
    for (int p = 0; p < 4; ++p) {  // Vt tile [128][64] -> [128][72]
      int h = p * 32 + vrow;
      *(u16x8*)&Vl[h * 72 + vcol] =
          *(const u16x8*)&Vg0[(size_t)h * T_DIM + kv0 + vcol];
    }
    __syncthreads();

    // S = Q K^T (Q prescaled): 4 col-frags x 4 k-chunks
    f32x4 s[4];
#pragma unroll
    for (int nf = 0; nf < 4; ++nf) {
      f32x4 a = {0.f, 0.f, 0.f, 0.f};
#pragma unroll
      for (int kk = 0; kk < 4; ++kk) {
        u16x8 kf = *(const u16x8*)&Kl[(nf * 16 + lq) * 136 + kk * 32 + g * 8];
        a = mfma16x16(qf[kk], kf, a);
      }
      s[nf] = a;
    }

    if (kv0 == q0) {  // diagonal tile: causal mask (col > row)
      int row = wave * 16 + g * 4;
#pragma unroll
      for (int nf = 0; nf < 4; ++nf) {
        int col = nf * 16 + lq;
#pragma unroll
        for (int r = 0; r < 4; ++r)
          if (col > row + r) s[nf][r] = -INFINITY;
      }
    }

    // online softmax; rows 4g..4g+3 live in 16-lane group g
    float mloc[4];
#pragma unroll
    for (int r = 0; r < 4; ++r)
      mloc[r] = fmaxf(fmaxf(s[0][r], s[1][r]), fmaxf(s[2][r], s[3][r]));
#pragma unroll
    for (int off = 1; off < 16; off <<= 1)
#pragma unroll
      for (int r = 0; r < 4; ++r)
        mloc[r] = fmaxf(mloc[r], __shfl_xor(mloc[r], off));

    float al[4], ps[4];
#pragma unroll
    for (int r = 0; r < 4; ++r) {
      float mn = fmaxf(m_run[r], mloc[r]);
      al[r] = __expf(m_run[r] - mn);
      m_run[r] = mn;
      ps[r] = 0.f;
    }
#pragma unroll
    for (int nf = 0; nf < 4; ++nf)
#pragma unroll
      for (int r = 0; r < 4; ++r) {
        float p = __expf(s[nf][r] - m_run[r]);
        s[nf][r] = p;
        ps[r] += p;
      }
#pragma unroll
    for (int off = 1; off < 16; off <<= 1)
#pragma unroll
      for (int r = 0; r < 4; ++r) ps[r] += __shfl_xor(ps[r], off);
#pragma unroll
    for (int r = 0; r < 4; ++r) l_run[r] = l_run[r] * al[r] + ps[r];
#pragma unroll
    for (int h8 = 0; h8 < 8; ++h8)
#pragma unroll
      for (int r = 0; r < 4; ++r) ao[h8][r] *= al[r];

    // P (D-layout) -> per-wave LDS -> A-layout frags for PV
#pragma unroll
    for (int nf = 0; nf < 4; ++nf)
#pragma unroll
      for (int r = 0; r < 4; ++r)
        Pl[wave][(g * 4 + r) * 72 + nf * 16 + lq] = f2bf(s[nf][r]);

#pragma unroll
    for (int kk = 0; kk < 2; ++kk) {
      u16x8 pf = *(const u16x8*)&Pl[wave][lq * 72 + kk * 32 + g * 8];
#pragma unroll
      for (int h8 = 0; h8 < 8; ++h8) {
        u16x8 vf = *(const u16x8*)&Vl[(h8 * 16 + lq) * 72 + kk * 32 + g * 8];
        ao[h8] = mfma16x16(pf, vf, ao[h8]);
      }
    }
  }

  if (!split) {
    float inv[4];
#pragma unroll
    for (int r = 0; r < 4; ++r) inv[r] = 1.f / l_run[r];
    float* Og = out + (size_t)(b * T_DIM + q0 + wave * 16) * H_DIM;
#pragma unroll
    for (int h8 = 0; h8 < 8; ++h8)
#pragma unroll
      for (int r = 0; r < 4; ++r)
        Og[(size_t)(g * 4 + r) * H_DIM + h8 * 16 + lq] = ao[h8][r] * inv[r];
  } else {
    float* Op = Opart + (size_t)pid * 8192 + (size_t)(wave * 16) * H_DIM;
#pragma unroll
    for (int h8 = 0; h8 < 8; ++h8)
#pragma unroll
      for (int r = 0; r < 4; ++r)
        Op[(size_t)(g * 4 + r) * H_DIM + h8 * 16 + lq] = ao[h8][r];
    if (lq == 0) {
      float* mlp = ml + (size_t)pid * 128;
#pragma unroll
      for (int r = 0; r < 4; ++r) {
        mlp[wave * 16 + g * 4 + r] = m_run[r];
        mlp[64 + wave * 16 + g * 4 + r] = l_run[r];
      }
    }
  }
}

// --------------------------------------------------------------- combine ----
// grid (64, 4): merge the <=8 kv-split partials of one q-tile.
__global__ __launch_bounds__(256) void combine_kernel(
    const float* __restrict__ Opart, const float* __restrict__ ml,
    float* __restrict__ out) {
  const int qt = blockIdx.x, b = blockIdx.y;
  const int t = threadIdx.x;
  const int row = t >> 2;
  const int colb = (t & 3) * 32;
  const int gg = qt >> 3;
  const int n = gg + 1;
  const int base_e = 4 * gg * (gg + 1) + (qt - 8 * gg) * n;
  const int pid0 = b * NPB + base_e;

  float mv[8];
#pragma unroll
  for (int i = 0; i < 8; ++i)
    mv[i] = (i < n) ? ml[(size_t)(pid0 + i) * 128 + row] : -INFINITY;
  float M = mv[0];
#pragma unroll
  for (int i = 1; i < 8; ++i) M = fmaxf(M, mv[i]);

  float L = 0.f;
  f32x4 o[8] = {};
#pragma unroll
  for (int i = 0; i < 8; ++i)
    if (i < n) {
      float sc = __expf(mv[i] - M);
      L += sc * ml[(size_t)(pid0 + i) * 128 + 64 + row];
      const f32x4* Op = (const f32x4*)(Opart + (size_t)(pid0 + i) * 8192 +
                                       (size_t)row * H_DIM + colb);
#pragma unroll
      for (int p = 0; p < 8; ++p) o[p] += sc * Op[p];
    }
  float inv = 1.f / L;
  f32x4* Og = (f32x4*)(out + ((size_t)b * T_DIM + qt * 64 + row) * H_DIM + colb);
#pragma unroll
  for (int p = 0; p < 8; ++p) Og[p] = o[p] * inv;
}

// ---------------------------------------------------------------- launch ----
extern "C" void kernel_launch(void* const* d_in, const int* in_sizes, int n_in,
                              void* d_out, int out_size, void* d_ws,
                              size_t ws_size, hipStream_t stream) {
  const float* x = (const float*)d_in[0];
  const float* wk = (const float*)d_in[1];
  const float* wq = (const float*)d_in[2];
  const float* wv = (const float*)d_in[3];
  float* out = (float*)d_out;
  char* ws = (char*)d_ws;

  u16* Wt = (u16*)ws;
  u16* Qb = (u16*)(ws + 786432);
  u16* Kb = (u16*)(ws + 786432 + 4194304);
  u16* Vt = (u16*)(ws + 786432 + 8388608);
  float* Opart = (float*)(ws + 13369344);
  float* ml = (float*)(ws + 51118080);

  const int split = (ws_size >= WS_SPLIT_NEED) ? 1 : 0;

  prep_w_kernel<<<1536, 256, 0, stream>>>(wk, wq, wv, Wt);
  proj_kernel<<<256, 256, 0, stream>>>(x, Wt, Qb, Kb, Vt);
  if (split) {
    attn_kernel<<<dim3(NPB, 4), 256, 0, stream>>>(Qb, Kb, Vt, out, Opart, ml, 1);
    combine_kernel<<<dim3(64, 4), 256, 0, stream>>>(Opart, ml, out);
  } else {
    attn_kernel<<<256, 256, 0, stream>>>(Qb, Kb, Vt, out, Opart, ml, 0);
  }
}